// Round 1
// baseline (755.687 us; speedup 1.0000x reference)
//
#include <hip/hip_runtime.h>

// KoopmanMlpExtractor fused bf16-MFMA kernel for gfx950.
//
// Design:
//  - All heavy math is one logical GEMM: X[B,512] (bf16) x Wcat[1600,512]^T,
//    Wcat rows = {W1(256), W2(256), A1(512), A2(512), Wc1(64)}.
//    Quadratic forms use x'Ax == x'A^T x so every B-fragment is 8 contiguous
//    bf16 from a weight ROW (single uniform load path from L2-resident ws).
//  - Per block: 64 samples. X tile lives in LDS (bf16, XOR-swizzled
//    byte ^= (row&7)<<4 to kill the stride-1024B 16-way bank conflict).
//  - Phases: stage X -> chooser GEMM (h=relu(xWc1^T+bc1)) -> sigma + b'x+c
//    (VALU) -> 48 paired chunk-GEMMs (W1/W2 -> gated actor write; A1/A2 ->
//    q += T*x fused reduction) -> cross-lane/wave reduce -> critic write.
//  - MFMA A/B k-mapping assumed k=(lane>>4)*8+j; correct under any true
//    mapping by shared-k-permutation invariance (A/B duality). C/D layout
//    col=lane&15, row=(lane>>4)*4+reg (HW-verified).

typedef __attribute__((ext_vector_type(8))) short short8;
typedef __attribute__((ext_vector_type(4))) float f32x4;

#define BATCH 65536
#define DIM 512
#define OUT 256
#define BM 64

__device__ __forceinline__ unsigned short f2bf(float f) {
  unsigned int u = __float_as_uint(f);
  u += 0x7FFFu + ((u >> 16) & 1u);   // round-to-nearest-even
  return (unsigned short)(u >> 16);
}
__device__ __forceinline__ float bf2f(unsigned short h) {
  return __uint_as_float(((unsigned int)h) << 16);
}

// ---------------- weight prep: fp32 -> bf16 Wcat[1600][512] in ws ----------
__global__ __launch_bounds__(256) void prep_kernel(
    const float* __restrict__ W1, const float* __restrict__ W2,
    const float* __restrict__ A1, const float* __restrict__ A2,
    const float* __restrict__ Wc1, unsigned short* __restrict__ Wcat) {
  int i = blockIdx.x * 256 + threadIdx.x;          // one thread per 4 elems
  if (i >= (1600 * 512) / 4) return;
  int e = i << 2;
  int row = e >> 9;
  int k = e & 511;
  const float* src;
  if (row < 256)       src = W1  + ((size_t)row << 9);
  else if (row < 512)  src = W2  + ((size_t)(row - 256) << 9);
  else if (row < 1024) src = A1  + ((size_t)(row - 512) << 9);
  else if (row < 1536) src = A2  + ((size_t)(row - 1024) << 9);
  else                 src = Wc1 + ((size_t)(row - 1536) << 9);
  float4 v = *reinterpret_cast<const float4*>(src + k);
  ushort4 o;
  o.x = f2bf(v.x); o.y = f2bf(v.y); o.z = f2bf(v.z); o.w = f2bf(v.w);
  *reinterpret_cast<ushort4*>(Wcat + e) = o;
}

// A-fragment from swizzled LDS X tile: row, k-tile byte kb, lane-high lh
__device__ __forceinline__ short8 ldsA(const unsigned short* Xs, int row, int kb, int lh) {
  int inner = (kb + (lh << 4)) ^ ((row & 7) << 4);
  return *reinterpret_cast<const short8*>(
      reinterpret_cast<const char*>(Xs) + row * 1024 + inner);
}
// B-fragment straight from global (L2-resident Wcat row n)
__device__ __forceinline__ short8 ldgB(const unsigned short* Wcat, int n, int kb, int lh) {
  return *reinterpret_cast<const short8*>(
      reinterpret_cast<const char*>(Wcat) + (size_t)n * 1024 + kb + (lh << 4));
}

__global__ __launch_bounds__(256, 2) void koop_kernel(
    const float* __restrict__ x,
    const float* __restrict__ b1, const float* __restrict__ c1,
    const float* __restrict__ b2, const float* __restrict__ c2,
    const float* __restrict__ bc1, const float* __restrict__ Wc2,
    const float* __restrict__ bc2,
    const unsigned short* __restrict__ Wcat,
    float* __restrict__ out) {
  __shared__ unsigned short Xs[BM * DIM];   // 64 KB, XOR-swizzled rows
  __shared__ unsigned short Hs[BM * 72];    // chooser hidden, padded stride 72
  __shared__ float sig[BM][2];
  __shared__ float qbs[BM][2];              // b'x + c per row, per quadratic
  __shared__ float qred[4][2][BM];          // per-wave partial q1/q2

  const int tid = threadIdx.x;
  const int w  = tid >> 6;
  const int l  = tid & 63;
  const int ll = l & 15;    // MFMA: A row-low / B col / D col
  const int lh = l >> 4;    // MFMA: k-group / D row-high
  const int r0 = blockIdx.x * BM;

  // ---- Phase 1: stage X tile fp32->bf16 into swizzled LDS ----
  #pragma unroll
  for (int it = 0; it < 16; ++it) {
    int g   = it * 256 + tid;        // 0..4095 groups of 8 elems
    int row = g >> 6;
    int k0  = (g & 63) << 3;
    const float* xp = x + (size_t)(r0 + row) * DIM + k0;
    float4 v0 = *reinterpret_cast<const float4*>(xp);
    float4 v1 = *reinterpret_cast<const float4*>(xp + 4);
    short8 xb;
    xb[0] = (short)f2bf(v0.x); xb[1] = (short)f2bf(v0.y);
    xb[2] = (short)f2bf(v0.z); xb[3] = (short)f2bf(v0.w);
    xb[4] = (short)f2bf(v1.x); xb[5] = (short)f2bf(v1.y);
    xb[6] = (short)f2bf(v1.z); xb[7] = (short)f2bf(v1.w);
    int inner = (k0 << 1) ^ ((row & 7) << 4);
    *reinterpret_cast<short8*>(reinterpret_cast<char*>(Xs) + row * 1024 + inner) = xb;
  }
  __syncthreads();

  // ---- Phase 2: chooser GEMM  h = relu(x @ Wc1^T + bc1)  (wave w: 16 cols)
  {
    f32x4 zero = {0.f, 0.f, 0.f, 0.f};
    f32x4 acc[4] = {zero, zero, zero, zero};
    int n0 = 1536 + (w << 4);
    #pragma unroll
    for (int kt = 0; kt < 16; ++kt) {
      int kb = kt << 6;
      short8 bf = ldgB(Wcat, n0 + ll, kb, lh);
      #pragma unroll
      for (int mf = 0; mf < 4; ++mf) {
        short8 af = ldsA(Xs, (mf << 4) + ll, kb, lh);
        acc[mf] = __builtin_amdgcn_mfma_f32_16x16x32_bf16(af, bf, acc[mf], 0, 0, 0);
      }
    }
    int hc = (w << 4) + ll;
    float bb = bc1[hc];
    #pragma unroll
    for (int mf = 0; mf < 4; ++mf)
      #pragma unroll
      for (int r = 0; r < 4; ++r) {
        int row = (mf << 4) + (lh << 2) + r;
        float h = acc[mf][r] + bb;
        Hs[row * 72 + hc] = f2bf(h > 0.f ? h : 0.f);
      }
  }
  __syncthreads();

  // ---- Phase 3: sigma (waves 0-1) and b'x + c (waves 2-3) ----
  if (tid < 128) {
    int row = tid & 63, j = tid >> 6;
    float s = bc2[j];
    #pragma unroll 8
    for (int c = 0; c < 64; ++c) s += bf2f(Hs[row * 72 + c]) * Wc2[j * 64 + c];
    sig[row][j] = 1.f / (1.f + __expf(-s));
  } else {
    int t = tid - 128;
    int row = t & 63, j = t >> 6;
    const float* bv = j ? b2 : b1;
    float acc = j ? c2[0] : c1[0];
    int swz = (row & 7) << 4;
    for (int k0 = 0; k0 < DIM; k0 += 8) {
      short8 xv = *reinterpret_cast<const short8*>(
          reinterpret_cast<const char*>(Xs) + row * 1024 + ((k0 << 1) ^ swz));
      #pragma unroll
      for (int jj = 0; jj < 8; ++jj)
        acc += bf2f((unsigned short)xv[jj]) * bv[k0 + jj];
    }
    qbs[row][j] = acc;
  }
  __syncthreads();

  // ---- Phase 4: 48 paired chunk-GEMMs (16 actor pairs, 32 critic pairs) ----
  float q1p[4][4], q2p[4][4];
  #pragma unroll
  for (int mf = 0; mf < 4; ++mf)
    #pragma unroll
    for (int r = 0; r < 4; ++r) { q1p[mf][r] = 0.f; q2p[mf][r] = 0.f; }

  #pragma unroll 1
  for (int t = 0; t < 12; ++t) {
    int p = w + (t << 2);                 // wave-uniform pair id 0..47
    f32x4 zero = {0.f, 0.f, 0.f, 0.f};
    f32x4 acc1[4] = {zero, zero, zero, zero};
    f32x4 acc2[4] = {zero, zero, zero, zero};
    int n0a, n0b;
    if (p < 16) { n0a = p << 4; n0b = 256 + (p << 4); }          // W1 / W2
    else        { n0a = 512 + ((p - 16) << 4); n0b = n0a + 512; } // A1 / A2
    #pragma unroll
    for (int kt = 0; kt < 16; ++kt) {
      int kb = kt << 6;
      short8 bfa = ldgB(Wcat, n0a + ll, kb, lh);
      short8 bfb = ldgB(Wcat, n0b + ll, kb, lh);
      #pragma unroll
      for (int mf = 0; mf < 4; ++mf) {
        short8 af = ldsA(Xs, (mf << 4) + ll, kb, lh);
        acc1[mf] = __builtin_amdgcn_mfma_f32_16x16x32_bf16(af, bfa, acc1[mf], 0, 0, 0);
        acc2[mf] = __builtin_amdgcn_mfma_f32_16x16x32_bf16(af, bfb, acc2[mf], 0, 0, 0);
      }
    }
    if (p < 16) {
      // actor: out = s0*y1 + s1*y2
      int col = n0a + ll;
      #pragma unroll
      for (int mf = 0; mf < 4; ++mf)
        #pragma unroll
        for (int r = 0; r < 4; ++r) {
          int row = (mf << 4) + (lh << 2) + r;
          float v = sig[row][0] * acc1[mf][r] + sig[row][1] * acc2[mf][r];
          out[(size_t)(r0 + row) * OUT + col] = v;
        }
    } else {
      // critic: q += T[row][n] * x[row][n]  (n = this chunk's A-columns)
      int cA = (n0a - 512) + ll;
      #pragma unroll
      for (int mf = 0; mf < 4; ++mf)
        #pragma unroll
        for (int r = 0; r < 4; ++r) {
          int row = (mf << 4) + (lh << 2) + r;
          float xv = bf2f(*reinterpret_cast<const unsigned short*>(
              reinterpret_cast<const char*>(Xs) + row * 1024 +
              (((cA << 1) ^ ((row & 7) << 4)))));
          q1p[mf][r] += acc1[mf][r] * xv;
          q2p[mf][r] += acc2[mf][r] * xv;
        }
    }
  }

  // reduce q partials across the 16 col-lanes (stays within lh groups)
  #pragma unroll
  for (int m = 1; m < 16; m <<= 1) {
    #pragma unroll
    for (int mf = 0; mf < 4; ++mf)
      #pragma unroll
      for (int r = 0; r < 4; ++r) {
        q1p[mf][r] += __shfl_xor(q1p[mf][r], m, 64);
        q2p[mf][r] += __shfl_xor(q2p[mf][r], m, 64);
      }
  }
  if (ll == 0) {
    #pragma unroll
    for (int mf = 0; mf < 4; ++mf)
      #pragma unroll
      for (int r = 0; r < 4; ++r) {
        int row = (mf << 4) + (lh << 2) + r;
        qred[w][0][row] = q1p[mf][r];
        qred[w][1][row] = q2p[mf][r];
      }
  }
  __syncthreads();

  if (tid < 64) {
    int row = tid;
    float q1 = qred[0][0][row] + qred[1][0][row] + qred[2][0][row] + qred[3][0][row];
    float q2 = qred[0][1][row] + qred[1][1][row] + qred[2][1][row] + qred[3][1][row];
    out[(size_t)BATCH * OUT + r0 + row] =
        sig[row][0] * (q1 + qbs[row][0]) + sig[row][1] * (q2 + qbs[row][1]);
  }
}

extern "C" void kernel_launch(void* const* d_in, const int* in_sizes, int n_in,
                              void* d_out, int out_size, void* d_ws, size_t ws_size,
                              hipStream_t stream) {
  const float* x   = (const float*)d_in[0];
  const float* W1  = (const float*)d_in[1];
  const float* W2  = (const float*)d_in[2];
  const float* A1  = (const float*)d_in[3];
  const float* b1  = (const float*)d_in[4];
  const float* c1  = (const float*)d_in[5];
  const float* A2  = (const float*)d_in[6];
  const float* b2  = (const float*)d_in[7];
  const float* c2  = (const float*)d_in[8];
  const float* Wc1 = (const float*)d_in[9];
  const float* bc1 = (const float*)d_in[10];
  const float* Wc2 = (const float*)d_in[11];
  const float* bc2 = (const float*)d_in[12];
  float* out = (float*)d_out;
  unsigned short* Wcat = (unsigned short*)d_ws;   // 1600*512*2 = 1.6 MB

  prep_kernel<<<(1600 * 512 / 4 + 255) / 256, 256, 0, stream>>>(W1, W2, A1, A2, Wc1, Wcat);
  koop_kernel<<<BATCH / BM, 256, 0, stream>>>(x, b1, c1, b2, c2, bc1, Wc2, bc2, Wcat, out);
}

// Round 8
// 578.430 us; speedup vs baseline: 1.3064x; 1.3064x over previous
//
#include <hip/hip_runtime.h>

// KoopmanMlpExtractor fused bf16-MFMA kernel for gfx950 — round 8 (= R3 resubmit;
// R3-R7 hit GPU-broker acquisition timeouts and never ran).
//
//  - One logical GEMM: X[B,512](bf16) x Wcat[1600,512]^T,
//    Wcat rows = {W1(256), W2(256), A1(512), A2(512), Wc1(64)} (x'Ax==x'A^Tx).
//  - vs R1 (HBM-traffic-bound: FETCH 832MB, WRITE 499MB):
//    * nontemporal x loads + out stores -> streams don't evict L2-resident Wcat
//    * actor pairs reassigned so wave w owns contiguous cols [64w,64w+64);
//      gated outputs buffered in regs (static idx) and burst-stored so every
//      128B line completes in one window (kills RMW/multi-evict amplification)
//    * explicit 1-deep B-fragment prefetch in each chunk GEMM
//  - nontemporal builtins need clang ext_vector types, not
//    HIP_vector_type<float,4>; use f32x4 (ext_vector) for the x loads.

typedef __attribute__((ext_vector_type(8))) short short8;
typedef __attribute__((ext_vector_type(4))) float f32x4;

#define BATCH 65536
#define DIM 512
#define OUT 256
#define BM 64

__device__ __forceinline__ unsigned short f2bf(float f) {
  unsigned int u = __float_as_uint(f);
  u += 0x7FFFu + ((u >> 16) & 1u);   // round-to-nearest-even
  return (unsigned short)(u >> 16);
}
__device__ __forceinline__ float bf2f(unsigned short h) {
  return __uint_as_float(((unsigned int)h) << 16);
}

// ---------------- weight prep: fp32 -> bf16 Wcat[1600][512] in ws ----------
__global__ __launch_bounds__(256) void prep_kernel(
    const float* __restrict__ W1, const float* __restrict__ W2,
    const float* __restrict__ A1, const float* __restrict__ A2,
    const float* __restrict__ Wc1, unsigned short* __restrict__ Wcat) {
  int i = blockIdx.x * 256 + threadIdx.x;          // one thread per 4 elems
  if (i >= (1600 * 512) / 4) return;
  int e = i << 2;
  int row = e >> 9;
  int k = e & 511;
  const float* src;
  if (row < 256)       src = W1  + ((size_t)row << 9);
  else if (row < 512)  src = W2  + ((size_t)(row - 256) << 9);
  else if (row < 1024) src = A1  + ((size_t)(row - 512) << 9);
  else if (row < 1536) src = A2  + ((size_t)(row - 1024) << 9);
  else                 src = Wc1 + ((size_t)(row - 1536) << 9);
  f32x4 v = *reinterpret_cast<const f32x4*>(src + k);
  ushort4 o;
  o.x = f2bf(v[0]); o.y = f2bf(v[1]); o.z = f2bf(v[2]); o.w = f2bf(v[3]);
  *reinterpret_cast<ushort4*>(Wcat + e) = o;
}

// A-fragment from swizzled LDS X tile: row, k-tile byte kb, lane-high lh
__device__ __forceinline__ short8 ldsA(const unsigned short* Xs, int row, int kb, int lh) {
  int inner = (kb + (lh << 4)) ^ ((row & 7) << 4);
  return *reinterpret_cast<const short8*>(
      reinterpret_cast<const char*>(Xs) + row * 1024 + inner);
}
// B-fragment straight from global (L2-resident Wcat row n)
__device__ __forceinline__ short8 ldgB(const unsigned short* Wcat, int n, int kb, int lh) {
  return *reinterpret_cast<const short8*>(
      reinterpret_cast<const char*>(Wcat) + (size_t)n * 1024 + kb + (lh << 4));
}

// Paired 16x16x512 chunk GEMM with 1-deep B prefetch.
__device__ __forceinline__ void chunk_gemm(
    const unsigned short* __restrict__ Wcat, const unsigned short* Xs,
    int n0a, int n0b, int ll, int lh, f32x4 acc1[4], f32x4 acc2[4]) {
  short8 bfa = ldgB(Wcat, n0a + ll, 0, lh);
  short8 bfb = ldgB(Wcat, n0b + ll, 0, lh);
  #pragma unroll
  for (int kt = 0; kt < 16; ++kt) {
    short8 cbfa = bfa, cbfb = bfb;
    if (kt < 15) {
      bfa = ldgB(Wcat, n0a + ll, (kt + 1) << 6, lh);
      bfb = ldgB(Wcat, n0b + ll, (kt + 1) << 6, lh);
    }
    #pragma unroll
    for (int mf = 0; mf < 4; ++mf) {
      short8 af = ldsA(Xs, (mf << 4) + ll, kt << 6, lh);
      acc1[mf] = __builtin_amdgcn_mfma_f32_16x16x32_bf16(af, cbfa, acc1[mf], 0, 0, 0);
      acc2[mf] = __builtin_amdgcn_mfma_f32_16x16x32_bf16(af, cbfb, acc2[mf], 0, 0, 0);
    }
  }
}

__global__ __launch_bounds__(256, 2) void koop_kernel(
    const float* __restrict__ x,
    const float* __restrict__ b1, const float* __restrict__ c1,
    const float* __restrict__ b2, const float* __restrict__ c2,
    const float* __restrict__ bc1, const float* __restrict__ Wc2,
    const float* __restrict__ bc2,
    const unsigned short* __restrict__ Wcat,
    float* __restrict__ out) {
  __shared__ unsigned short Xs[BM * DIM];   // 64 KB, XOR-swizzled rows
  __shared__ unsigned short Hs[BM * 72];    // chooser hidden, padded stride 72
  __shared__ float sig[BM][2];
  __shared__ float qbs[BM][2];              // b'x + c per row, per quadratic
  __shared__ float qred[4][2][BM];          // per-wave partial q1/q2

  const int tid = threadIdx.x;
  const int w  = tid >> 6;
  const int l  = tid & 63;
  const int ll = l & 15;    // MFMA: A row-low / B col / D col
  const int lh = l >> 4;    // MFMA: k-group / D row-high
  const int r0 = blockIdx.x * BM;

  // ---- Phase 1: stage X tile fp32->bf16 into swizzled LDS (nt loads) ----
  #pragma unroll
  for (int it = 0; it < 16; ++it) {
    int g   = it * 256 + tid;        // 0..4095 groups of 8 elems
    int row = g >> 6;
    int k0  = (g & 63) << 3;
    const float* xp = x + (size_t)(r0 + row) * DIM + k0;
    f32x4 v0 = __builtin_nontemporal_load(reinterpret_cast<const f32x4*>(xp));
    f32x4 v1 = __builtin_nontemporal_load(reinterpret_cast<const f32x4*>(xp) + 1);
    short8 xb;
    xb[0] = (short)f2bf(v0[0]); xb[1] = (short)f2bf(v0[1]);
    xb[2] = (short)f2bf(v0[2]); xb[3] = (short)f2bf(v0[3]);
    xb[4] = (short)f2bf(v1[0]); xb[5] = (short)f2bf(v1[1]);
    xb[6] = (short)f2bf(v1[2]); xb[7] = (short)f2bf(v1[3]);
    int inner = (k0 << 1) ^ ((row & 7) << 4);
    *reinterpret_cast<short8*>(reinterpret_cast<char*>(Xs) + row * 1024 + inner) = xb;
  }
  __syncthreads();

  // ---- Phase 2: chooser GEMM  h = relu(x @ Wc1^T + bc1)  (wave w: 16 cols)
  {
    f32x4 zero = {0.f, 0.f, 0.f, 0.f};
    f32x4 acc[4] = {zero, zero, zero, zero};
    int n0 = 1536 + (w << 4);
    #pragma unroll
    for (int kt = 0; kt < 16; ++kt) {
      int kb = kt << 6;
      short8 bf = ldgB(Wcat, n0 + ll, kb, lh);
      #pragma unroll
      for (int mf = 0; mf < 4; ++mf) {
        short8 af = ldsA(Xs, (mf << 4) + ll, kb, lh);
        acc[mf] = __builtin_amdgcn_mfma_f32_16x16x32_bf16(af, bf, acc[mf], 0, 0, 0);
      }
    }
    int hc = (w << 4) + ll;
    float bb = bc1[hc];
    #pragma unroll
    for (int mf = 0; mf < 4; ++mf)
      #pragma unroll
      for (int r = 0; r < 4; ++r) {
        int row = (mf << 4) + (lh << 2) + r;
        float h = acc[mf][r] + bb;
        Hs[row * 72 + hc] = f2bf(h > 0.f ? h : 0.f);
      }
  }
  __syncthreads();

  // ---- Phase 3: sigma (waves 0-1) and b'x + c (waves 2-3) ----
  if (tid < 128) {
    int row = tid & 63, j = tid >> 6;
    float s = bc2[j];
    #pragma unroll 8
    for (int c = 0; c < 64; ++c) s += bf2f(Hs[row * 72 + c]) * Wc2[j * 64 + c];
    sig[row][j] = 1.f / (1.f + __expf(-s));
  } else {
    int t = tid - 128;
    int row = t & 63, j = t >> 6;
    const float* bv = j ? b2 : b1;
    float acc = j ? c2[0] : c1[0];
    int swz = (row & 7) << 4;
    for (int k0 = 0; k0 < DIM; k0 += 8) {
      short8 xv = *reinterpret_cast<const short8*>(
          reinterpret_cast<const char*>(Xs) + row * 1024 + ((k0 << 1) ^ swz));
      #pragma unroll
      for (int jj = 0; jj < 8; ++jj)
        acc += bf2f((unsigned short)xv[jj]) * bv[k0 + jj];
    }
    qbs[row][j] = acc;
  }
  __syncthreads();

  // ---- Phase 4a: actor — wave w owns contiguous cols [64w, 64w+64) ----
  // Buffer gated outputs in regs (static indexing), burst-store at the end
  // so every 128B out line completes within one instruction window.
  float gact[4][4][4];                      // [i=chunk][mf][r]
  #pragma unroll
  for (int i = 0; i < 4; ++i) {
    int p = (w << 2) + i;                   // pair 0..15, cols p*16..p*16+15
    f32x4 zero = {0.f, 0.f, 0.f, 0.f};
    f32x4 acc1[4] = {zero, zero, zero, zero};
    f32x4 acc2[4] = {zero, zero, zero, zero};
    chunk_gemm(Wcat, Xs, p << 4, 256 + (p << 4), ll, lh, acc1, acc2);
    #pragma unroll
    for (int mf = 0; mf < 4; ++mf)
      #pragma unroll
      for (int r = 0; r < 4; ++r) {
        int row = (mf << 4) + (lh << 2) + r;
        gact[i][mf][r] = sig[row][0] * acc1[mf][r] + sig[row][1] * acc2[mf][r];
      }
  }
  // burst nt stores: per row, 4 chunks x 64B back-to-back = 256B contiguous
  #pragma unroll
  for (int mf = 0; mf < 4; ++mf)
    #pragma unroll
    for (int r = 0; r < 4; ++r) {
      int row = (mf << 4) + (lh << 2) + r;
      float* po = out + (size_t)(r0 + row) * OUT + (w << 6) + ll;
      #pragma unroll
      for (int i = 0; i < 4; ++i)
        __builtin_nontemporal_store(gact[i][mf][r], po + (i << 4));
    }

  // ---- Phase 4b: critic — wave w owns A-col chunks [8w, 8w+8) ----
  float q1p[4][4], q2p[4][4];
  #pragma unroll
  for (int mf = 0; mf < 4; ++mf)
    #pragma unroll
    for (int r = 0; r < 4; ++r) { q1p[mf][r] = 0.f; q2p[mf][r] = 0.f; }

  #pragma unroll 1
  for (int t = 0; t < 8; ++t) {
    int pc = (w << 3) + t;                  // 0..31, A-cols pc*16..pc*16+15
    f32x4 zero = {0.f, 0.f, 0.f, 0.f};
    f32x4 acc1[4] = {zero, zero, zero, zero};
    f32x4 acc2[4] = {zero, zero, zero, zero};
    int n0a = 512 + (pc << 4);
    chunk_gemm(Wcat, Xs, n0a, n0a + 512, ll, lh, acc1, acc2);
    int cA = (pc << 4) + ll;
    #pragma unroll
    for (int mf = 0; mf < 4; ++mf)
      #pragma unroll
      for (int r = 0; r < 4; ++r) {
        int row = (mf << 4) + (lh << 2) + r;
        float xv = bf2f(*reinterpret_cast<const unsigned short*>(
            reinterpret_cast<const char*>(Xs) + row * 1024 +
            (((cA << 1) ^ ((row & 7) << 4)))));
        q1p[mf][r] += acc1[mf][r] * xv;
        q2p[mf][r] += acc2[mf][r] * xv;
      }
  }

  // reduce q partials across the 16 col-lanes (stays within lh groups)
  #pragma unroll
  for (int m = 1; m < 16; m <<= 1) {
    #pragma unroll
    for (int mf = 0; mf < 4; ++mf)
      #pragma unroll
      for (int r = 0; r < 4; ++r) {
        q1p[mf][r] += __shfl_xor(q1p[mf][r], m, 64);
        q2p[mf][r] += __shfl_xor(q2p[mf][r], m, 64);
      }
  }
  if (ll == 0) {
    #pragma unroll
    for (int mf = 0; mf < 4; ++mf)
      #pragma unroll
      for (int r = 0; r < 4; ++r) {
        int row = (mf << 4) + (lh << 2) + r;
        qred[w][0][row] = q1p[mf][r];
        qred[w][1][row] = q2p[mf][r];
      }
  }
  __syncthreads();

  if (tid < 64) {
    int row = tid;
    float q1 = qred[0][0][row] + qred[1][0][row] + qred[2][0][row] + qred[3][0][row];
    float q2 = qred[0][1][row] + qred[1][1][row] + qred[2][1][row] + qred[3][1][row];
    __builtin_nontemporal_store(
        sig[row][0] * (q1 + qbs[row][0]) + sig[row][1] * (q2 + qbs[row][1]),
        out + (size_t)BATCH * OUT + r0 + row);
  }
}

extern "C" void kernel_launch(void* const* d_in, const int* in_sizes, int n_in,
                              void* d_out, int out_size, void* d_ws, size_t ws_size,
                              hipStream_t stream) {
  const float* x   = (const float*)d_in[0];
  const float* W1  = (const float*)d_in[1];
  const float* W2  = (const float*)d_in[2];
  const float* A1  = (const float*)d_in[3];
  const float* b1  = (const float*)d_in[4];
  const float* c1  = (const float*)d_in[5];
  const float* A2  = (const float*)d_in[6];
  const float* b2  = (const float*)d_in[7];
  const float* c2  = (const float*)d_in[8];
  const float* Wc1 = (const float*)d_in[9];
  const float* bc1 = (const float*)d_in[10];
  const float* Wc2 = (const float*)d_in[11];
  const float* bc2 = (const float*)d_in[12];
  float* out = (float*)d_out;
  unsigned short* Wcat = (unsigned short*)d_ws;   // 1600*512*2 = 1.6 MB

  prep_kernel<<<(1600 * 512 / 4 + 255) / 256, 256, 0, stream>>>(W1, W2, A1, A2, Wc1, Wcat);
  koop_kernel<<<BATCH / BM, 256, 0, stream>>>(x, b1, c1, b2, c2, bc1, Wc2, bc2, Wcat, out);
}